// Round 5
// baseline (234.531 us; speedup 1.0000x reference)
//
#include <hip/hip_runtime.h>
#include <hip/hip_bf16.h>

typedef __bf16 bf16x8 __attribute__((ext_vector_type(8)));
typedef __bf16 bf16x4 __attribute__((ext_vector_type(4)));
typedef float f32x4 __attribute__((ext_vector_type(4)));

#define NROW 3072
#define NF 512            // IN_F == H*D == 512
#define NH 8
#define ND 64

// ---------------------------------------------------------------------------
// Kernel 0: convert x and W fp32 -> bf16 (vectorized)
// ---------------------------------------------------------------------------
__global__ __launch_bounds__(256) void k_convert(const float* __restrict__ s0,
                                                 const float* __restrict__ s1,
                                                 __bf16* __restrict__ d0,
                                                 __bf16* __restrict__ d1) {
    const int n0 = NROW * NF / 4, n1 = NF * NF / 4;
    int total = n0 + n1;
    for (int i = blockIdx.x * 256 + threadIdx.x; i < total; i += gridDim.x * 256) {
        const float4* s; __bf16* d; int k = i;
        if (k < n0) { s = (const float4*)s0; d = d0; }
        else { k -= n0; s = (const float4*)s1; d = d1; }
        float4 v = s[k];
        bf16x4 o = { (__bf16)v.x, (__bf16)v.y, (__bf16)v.z, (__bf16)v.w };
        *reinterpret_cast<bf16x4*>(d + k * 4) = o;
    }
}

// ---------------------------------------------------------------------------
// Kernel 1: h = x @ W^T; write h (direct) and hT (via LDS transpose, 8B chunks)
// ---------------------------------------------------------------------------
__global__ __launch_bounds__(256) void k_gemm_h(const __bf16* __restrict__ x,
                                                const __bf16* __restrict__ W,
                                                __bf16* __restrict__ h,
                                                __bf16* __restrict__ hT) {
    __shared__ __bf16 tile[4][16][17];      // [wave][i][o], padded
    int wave = threadIdx.x >> 6;
    int lane = threadIdx.x & 63;
    int t = blockIdx.x * 4 + wave;          // 6144 tiles: 192 i-tiles x 32 o-tiles
    int i0 = (t >> 5) << 4;
    int o0 = (t & 31) << 4;
    int fr = lane & 15;
    int quad = lane >> 4;

    const bf16x8* xa = reinterpret_cast<const bf16x8*>(x + (i0 + fr) * NF + quad * 8);
    const bf16x8* wb = reinterpret_cast<const bf16x8*>(W + (o0 + fr) * NF + quad * 8);

    f32x4 acc = {0.f, 0.f, 0.f, 0.f};
#pragma unroll
    for (int k = 0; k < 16; ++k) {
        bf16x8 a = xa[k * 4];
        bf16x8 b = wb[k * 4];
        acc = __builtin_amdgcn_mfma_f32_16x16x32_bf16(a, b, acc, 0, 0, 0);
    }
    // D: row m = quad*4+r (i), col n = fr (o)
#pragma unroll
    for (int r = 0; r < 4; ++r) {
        __bf16 v = (__bf16)acc[r];
        h[(i0 + quad * 4 + r) * NF + o0 + fr] = v;   // 32B-chunk coalesced
        tile[wave][quad * 4 + r][fr] = v;
    }
    __syncthreads();
    // hT write: lane -> o-row (lane>>2), i-chunk of 4 ((lane&3)*4)
    int orow = lane >> 2;
    int li = (lane & 3) * 4;
    bf16x4 o4 = { tile[wave][li][orow], tile[wave][li + 1][orow],
                  tile[wave][li + 2][orow], tile[wave][li + 3][orow] };
    *reinterpret_cast<bf16x4*>(hT + (o0 + orow) * NROW + i0 + li) = o4;
}

// ---------------------------------------------------------------------------
// Kernel 2: e_src[n,h] = <h[n,h,:], a_src[h,:]>, e_dst likewise. fp32 out.
// ---------------------------------------------------------------------------
__global__ __launch_bounds__(64) void k_edges(const __bf16* __restrict__ h,
                                              const float* __restrict__ a_src,
                                              const float* __restrict__ a_dst,
                                              float* __restrict__ e_src,
                                              float* __restrict__ e_dst) {
    int n = blockIdx.x;
    int lane = threadIdx.x;
    bf16x8 hv = *reinterpret_cast<const bf16x8*>(h + n * NF + lane * 8);
    const float4* asp = reinterpret_cast<const float4*>(a_src + lane * 8);
    const float4* adp = reinterpret_cast<const float4*>(a_dst + lane * 8);
    float4 as0 = asp[0], as1 = asp[1];
    float4 ad0 = adp[0], ad1 = adp[1];
    float asv[8] = {as0.x, as0.y, as0.z, as0.w, as1.x, as1.y, as1.z, as1.w};
    float adv[8] = {ad0.x, ad0.y, ad0.z, ad0.w, ad1.x, ad1.y, ad1.z, ad1.w};
    float ps = 0.f, pd = 0.f;
#pragma unroll
    for (int t = 0; t < 8; ++t) {
        float hh = (float)hv[t];
        ps += hh * asv[t];
        pd += hh * adv[t];
    }
#pragma unroll
    for (int off = 1; off < 8; off <<= 1) {
        ps += __shfl_xor(ps, off, 64);
        pd += __shfl_xor(pd, off, 64);
    }
    if ((lane & 7) == 0) {
        int head = lane >> 3;
        e_src[n * NH + head] = ps;
        e_dst[n * NH + head] = pd;
    }
}

// ---------------------------------------------------------------------------
// Kernel 3: colmax[h] = max_j e_dst[j,h]
// ---------------------------------------------------------------------------
__global__ __launch_bounds__(64) void k_colmax(const float* __restrict__ e_dst,
                                               float* __restrict__ colmax) {
    int head = blockIdx.x;
    int lane = threadIdx.x;
    float mx = -3e38f;
    for (int j = lane; j < NROW; j += 64) mx = fmaxf(mx, e_dst[j * NH + head]);
#pragma unroll
    for (int off = 1; off < 64; off <<= 1) mx = fmaxf(mx, __shfl_xor(mx, off, 64));
    if (lane == 0) colmax[head] = mx;
}

// ---------------------------------------------------------------------------
// Kernel 4: masked softmax-PV, factored exp, 128-j macro-tiles with all 24
// global loads issued before use (memory-level parallelism is the point).
// Grid: 48 i-blocks x JCV j-chunks x 8 heads; 4 waves; 16 rows/wave.
// ---------------------------------------------------------------------------
template <int JCV>
__global__ __launch_bounds__(256, 2) void k_attn(const int* __restrict__ adj,
                                                 const float* __restrict__ e_src,
                                                 const float* __restrict__ e_dst,
                                                 const float* __restrict__ colmax,
                                                 const __bf16* __restrict__ hT,
                                                 float* __restrict__ num,
                                                 float* __restrict__ den) {
    constexpr int JCHUNK = NROW / JCV;
    __shared__ __align__(16) float2 lds_pq[JCHUNK];
    int b = blockIdx.x;
    int head = b & 7;
    int jc = (b >> 3) & (JCV - 1);
    int i0 = (b >> 3) / JCV * 64;
    int jbase = jc * JCHUNK;
    int tid = threadIdx.x;
    int wave = tid >> 6, lane = tid & 63;
    int fr = lane & 15, quad = lane >> 4;

    float Mg = colmax[head];
    for (int j = tid; j < JCHUNK; j += 256) {
        float t = e_dst[(jbase + j) * NH + head] - Mg;   // <= 0
        lds_pq[j] = make_float2(__expf(t), __expf(0.2f * t));
    }
    __syncthreads();

    int irow = i0 + wave * 16 + fr;
    float s = e_src[irow * NH + head];
    float u = s + Mg;
    float A = (u > 0.f) ? 1.f : __expf(0.8f * u);
    float C = (u > 0.f) ? __expf(-0.8f * u) : 1.f;
    float T = __expf(-u);
    int selfj = irow - jbase - quad * 8;     // in-chunk self index, quad-shifted

    const int* adjrow = adj + irow * NROW + jbase + quad * 8;
    const __bf16* hTh = hT + (head * ND + fr) * NROW + jbase + quad * 8;

    f32x4 acc0 = {0,0,0,0}, acc1 = {0,0,0,0}, acc2 = {0,0,0,0}, acc3 = {0,0,0,0};
    float lsum = 0.f;

    for (int j0 = 0; j0 < JCHUNK; j0 += 128) {
        // --- issue ALL global loads for this macro-tile up front (24 in flight)
        int4 a[8];
#pragma unroll
        for (int sTile = 0; sTile < 4; ++sTile) {
            a[2 * sTile]     = *reinterpret_cast<const int4*>(adjrow + j0 + 32 * sTile);
            a[2 * sTile + 1] = *reinterpret_cast<const int4*>(adjrow + j0 + 32 * sTile + 4);
        }
        bf16x8 v[16];
#pragma unroll
        for (int sTile = 0; sTile < 4; ++sTile)
#pragma unroll
            for (int d = 0; d < 4; ++d)
                v[sTile * 4 + d] = *reinterpret_cast<const bf16x8*>(hTh + j0 + 32 * sTile + d * 16 * NROW);

        // --- consume: 4 sub-tiles of 32 j
#pragma unroll
        for (int sTile = 0; sTile < 4; ++sTile) {
            const float4* lp = reinterpret_cast<const float4*>(&lds_pq[j0 + 32 * sTile + quad * 8]);
            float4 q01 = lp[0], q23 = lp[1], q45 = lp[2], q67 = lp[3];
            float P[8] = {q01.x, q01.z, q23.x, q23.z, q45.x, q45.z, q67.x, q67.z};
            float Q[8] = {q01.y, q01.w, q23.y, q23.w, q45.y, q45.w, q67.y, q67.w};
            int av[8] = {a[2 * sTile].x, a[2 * sTile].y, a[2 * sTile].z, a[2 * sTile].w,
                         a[2 * sTile + 1].x, a[2 * sTile + 1].y, a[2 * sTile + 1].z, a[2 * sTile + 1].w};
            bf16x8 af;
#pragma unroll
            for (int t = 0; t < 8; ++t) {
                bool pos = P[t] > T;
                float p = (pos ? P[t] : Q[t]) * (pos ? A : C);
                bool valid = (av[t] > 0) || (j0 + 32 * sTile + t == selfj);
                p = valid ? p : 0.f;
                af[t] = (__bf16)p;
                lsum += (float)af[t];
            }
            acc0 = __builtin_amdgcn_mfma_f32_16x16x32_bf16(af, v[sTile * 4 + 0], acc0, 0, 0, 0);
            acc1 = __builtin_amdgcn_mfma_f32_16x16x32_bf16(af, v[sTile * 4 + 1], acc1, 0, 0, 0);
            acc2 = __builtin_amdgcn_mfma_f32_16x16x32_bf16(af, v[sTile * 4 + 2], acc2, 0, 0, 0);
            acc3 = __builtin_amdgcn_mfma_f32_16x16x32_bf16(af, v[sTile * 4 + 3], acc3, 0, 0, 0);
        }
    }

    lsum += __shfl_xor(lsum, 16, 64);
    lsum += __shfl_xor(lsum, 32, 64);    // lane L holds total for row (L&15)

    if (quad == 0)
        den[(jc * NROW + i0 + wave * 16 + fr) * NH + head] = lsum;

#pragma unroll
    for (int r = 0; r < 4; ++r) {
        int orow = quad * 4 + r;
        int ob = (jc * NROW + i0 + wave * 16 + orow) * NF + head * ND + fr;
        num[ob +  0] = acc0[r];
        num[ob + 16] = acc1[r];
        num[ob + 32] = acc2[r];
        num[ob + 48] = acc3[r];
    }
}

// ---------------------------------------------------------------------------
// Kernel 5: out[i,c] = sum_jc num[jc][i][c] / sum_jc den[jc][i][c>>6]
// ---------------------------------------------------------------------------
__global__ __launch_bounds__(256) void k_reduce(const float* __restrict__ num,
                                                const float* __restrict__ den,
                                                float* __restrict__ out, int jcv) {
    int idx = blockIdx.x * 256 + threadIdx.x;     // 0 .. NROW*NF
    int i = idx >> 9;
    int c = idx & 511;
    int head = c >> 6;
    float ns = 0.f, ds = 0.f;
    for (int k = 0; k < jcv; ++k) {
        ns += num[(k * NROW + i) * NF + c];
        ds += den[(k * NROW + i) * NH + head];
    }
    out[idx] = ns / fmaxf(ds, 1e-30f);
}

// ---------------------------------------------------------------------------
extern "C" void kernel_launch(void* const* d_in, const int* in_sizes, int n_in,
                              void* d_out, int out_size, void* d_ws, size_t ws_size,
                              hipStream_t stream) {
    const float* x_raw  = (const float*)d_in[0];
    const int*   adj    = (const int*)d_in[1];
    const float* W_raw  = (const float*)d_in[2];
    const float* as_raw = (const float*)d_in[3];
    const float* ad_raw = (const float*)d_in[4];
    float* out = (float*)d_out;

    char* ws = (char*)d_ws;
    __bf16* h      = (__bf16*)(ws);                      // 3,145,728 B
    __bf16* hT     = (__bf16*)(ws + 3145728);            // 3,145,728 B
    float*  e_src  = (float*)(ws + 6291456);             //    98,304 B
    float*  e_dst  = (float*)(ws + 6389760);             //    98,304 B
    float*  cmax   = (float*)(ws + 6488064);             //     1,024 B
    __bf16* xb     = (__bf16*)(ws + 6489088);            // 3,145,728 B
    __bf16* Wb     = (__bf16*)(ws + 9634816);            //   524,288 B
    float*  num    = (float*)(ws + 10159104);            // JC*6,291,456 B
    // den follows num

    // JC=4 needs 10159104 + 4*6291456 + 4*98304 = 35,718,144 B
    int jcv = (ws_size >= 35800000u) ? 4 : 1;
    float* den = (float*)(ws + 10159104 + (size_t)jcv * 6291456);

    k_convert<<<1024, 256, 0, stream>>>(x_raw, W_raw, xb, Wb);
    k_gemm_h<<<1536, 256, 0, stream>>>(xb, Wb, h, hT);
    k_edges<<<NROW, 64, 0, stream>>>(h, as_raw, ad_raw, e_src, e_dst);
    k_colmax<<<NH, 64, 0, stream>>>(e_dst, cmax);
    if (jcv == 4)
        k_attn<4><<<48 * 4 * 8, 256, 0, stream>>>(adj, e_src, e_dst, cmax, hT, num, den);
    else
        k_attn<1><<<48 * 1 * 8, 256, 0, stream>>>(adj, e_src, e_dst, cmax, hT, num, den);
    k_reduce<<<NROW * NF / 256, 256, 0, stream>>>(num, den, out, jcv);
}

// Round 6
// 223.204 us; speedup vs baseline: 1.0507x; 1.0507x over previous
//
#include <hip/hip_runtime.h>
#include <hip/hip_bf16.h>

typedef __bf16 bf16x8 __attribute__((ext_vector_type(8)));
typedef __bf16 bf16x4 __attribute__((ext_vector_type(4)));
typedef float f32x4 __attribute__((ext_vector_type(4)));

#define NROW 3072
#define NF 512            // IN_F == H*D == 512
#define NH 8
#define ND 64

// Order-preserving float<->uint key for atomicMax over signed floats.
__device__ __forceinline__ unsigned enc_key(float f) {
    unsigned u = __float_as_uint(f);
    return (f < 0.f) ? ~u : (u | 0x80000000u);
}
__device__ __forceinline__ float dec_key(unsigned k) {
    unsigned u = (k & 0x80000000u) ? (k ^ 0x80000000u) : ~k;
    return __uint_as_float(u);
}

// ---------------------------------------------------------------------------
// Kernel 0: convert x and W fp32 -> bf16 (vectorized); zero the maxkey slots.
// ---------------------------------------------------------------------------
__global__ __launch_bounds__(256) void k_convert(const float* __restrict__ s0,
                                                 const float* __restrict__ s1,
                                                 __bf16* __restrict__ d0,
                                                 __bf16* __restrict__ d1,
                                                 unsigned* __restrict__ maxkey) {
    if (blockIdx.x == 0 && threadIdx.x < NH) maxkey[threadIdx.x] = 0u;  // < any real key
    const int n0 = NROW * NF / 4, n1 = NF * NF / 4;
    int total = n0 + n1;
    for (int i = blockIdx.x * 256 + threadIdx.x; i < total; i += gridDim.x * 256) {
        const float4* s; __bf16* d; int k = i;
        if (k < n0) { s = (const float4*)s0; d = d0; }
        else { k -= n0; s = (const float4*)s1; d = d1; }
        float4 v = s[k];
        bf16x4 o = { (__bf16)v.x, (__bf16)v.y, (__bf16)v.z, (__bf16)v.w };
        *reinterpret_cast<bf16x4*>(d + k * 4) = o;
    }
}

// ---------------------------------------------------------------------------
// Kernel 1: pack (adj>0 || j==i) into a bitmask: bits[3072][96] u32 (1.18 MB).
// Ballot per 64-j group; one block per row.
// ---------------------------------------------------------------------------
__global__ __launch_bounds__(256) void k_bitpack(const int* __restrict__ adj,
                                                 unsigned long long* __restrict__ bits64) {
    int i = blockIdx.x;
    int wave = threadIdx.x >> 6, lane = threadIdx.x & 63;
    const int* row = adj + i * NROW;
#pragma unroll
    for (int it = 0; it < 12; ++it) {
        int base = wave * 768 + it * 64;
        int j = base + lane;
        bool pred = (row[j] > 0) || (j == i);
        unsigned long long bal = __ballot(pred);
        if (lane == 0) bits64[i * 48 + (base >> 6)] = bal;
    }
}

// ---------------------------------------------------------------------------
// Kernel 2: h = x @ W^T; write h (direct) and hT (via LDS transpose, 8B chunks)
// ---------------------------------------------------------------------------
__global__ __launch_bounds__(256) void k_gemm_h(const __bf16* __restrict__ x,
                                                const __bf16* __restrict__ W,
                                                __bf16* __restrict__ h,
                                                __bf16* __restrict__ hT) {
    __shared__ __bf16 tile[4][16][17];      // [wave][i][o], padded
    int wave = threadIdx.x >> 6;
    int lane = threadIdx.x & 63;
    int t = blockIdx.x * 4 + wave;          // 6144 tiles: 192 i-tiles x 32 o-tiles
    int i0 = (t >> 5) << 4;
    int o0 = (t & 31) << 4;
    int fr = lane & 15;
    int quad = lane >> 4;

    const bf16x8* xa = reinterpret_cast<const bf16x8*>(x + (i0 + fr) * NF + quad * 8);
    const bf16x8* wb = reinterpret_cast<const bf16x8*>(W + (o0 + fr) * NF + quad * 8);

    f32x4 acc = {0.f, 0.f, 0.f, 0.f};
#pragma unroll
    for (int k = 0; k < 16; ++k) {
        bf16x8 a = xa[k * 4];
        bf16x8 b = wb[k * 4];
        acc = __builtin_amdgcn_mfma_f32_16x16x32_bf16(a, b, acc, 0, 0, 0);
    }
#pragma unroll
    for (int r = 0; r < 4; ++r) {
        __bf16 v = (__bf16)acc[r];
        h[(i0 + quad * 4 + r) * NF + o0 + fr] = v;
        tile[wave][quad * 4 + r][fr] = v;
    }
    __syncthreads();
    int orow = lane >> 2;
    int li = (lane & 3) * 4;
    bf16x4 o4 = { tile[wave][li][orow], tile[wave][li + 1][orow],
                  tile[wave][li + 2][orow], tile[wave][li + 3][orow] };
    *reinterpret_cast<bf16x4*>(hT + (o0 + orow) * NROW + i0 + li) = o4;
}

// ---------------------------------------------------------------------------
// Kernel 3: e_src/e_dst dots + fused per-head col-max (encoded atomicMax).
// 4 rows per block (one per wave).
// ---------------------------------------------------------------------------
__global__ __launch_bounds__(256) void k_edges(const __bf16* __restrict__ h,
                                               const float* __restrict__ a_src,
                                               const float* __restrict__ a_dst,
                                               float* __restrict__ e_src,
                                               float* __restrict__ e_dst,
                                               unsigned* __restrict__ maxkey) {
    __shared__ unsigned skey[NH];
    if (threadIdx.x < NH) skey[threadIdx.x] = 0u;
    __syncthreads();
    int wave = threadIdx.x >> 6, lane = threadIdx.x & 63;
    int n = blockIdx.x * 4 + wave;
    bf16x8 hv = *reinterpret_cast<const bf16x8*>(h + n * NF + lane * 8);
    const float4* asp = reinterpret_cast<const float4*>(a_src + lane * 8);
    const float4* adp = reinterpret_cast<const float4*>(a_dst + lane * 8);
    float4 as0 = asp[0], as1 = asp[1];
    float4 ad0 = adp[0], ad1 = adp[1];
    float asv[8] = {as0.x, as0.y, as0.z, as0.w, as1.x, as1.y, as1.z, as1.w};
    float adv[8] = {ad0.x, ad0.y, ad0.z, ad0.w, ad1.x, ad1.y, ad1.z, ad1.w};
    float ps = 0.f, pd = 0.f;
#pragma unroll
    for (int t = 0; t < 8; ++t) {
        float hh = (float)hv[t];
        ps += hh * asv[t];
        pd += hh * adv[t];
    }
#pragma unroll
    for (int off = 1; off < 8; off <<= 1) {
        ps += __shfl_xor(ps, off, 64);
        pd += __shfl_xor(pd, off, 64);
    }
    if ((lane & 7) == 0) {
        int head = lane >> 3;
        e_src[n * NH + head] = ps;
        e_dst[n * NH + head] = pd;
        atomicMax(&skey[head], enc_key(pd));
    }
    __syncthreads();
    if (threadIdx.x < NH) atomicMax(&maxkey[threadIdx.x], skey[threadIdx.x]);
}

// ---------------------------------------------------------------------------
// Kernel 4: masked softmax-PV. Mask bits live in 24 registers per lane
// (loaded once); inner loop has ONLY 4 hT loads (L2/L1-resident: head==b&7
// keeps each XCD's L2 on one head's 0.8 MB hT slice + the 1.2 MB bitmask).
// Factored exp: p = mask * (P_j>T_i ? A_i*P_j : C_i*Q_j).
// Grid: 48 i-blocks x JCV j-chunks x 8 heads; 4 waves; 16 rows/wave.
// ---------------------------------------------------------------------------
template <int JCV>
__global__ __launch_bounds__(256) void k_attn(const unsigned* __restrict__ bits,
                                              const float* __restrict__ e_src,
                                              const float* __restrict__ e_dst,
                                              const unsigned* __restrict__ maxkey,
                                              const __bf16* __restrict__ hT,
                                              float* __restrict__ num,
                                              float* __restrict__ den) {
    constexpr int JCHUNK = NROW / JCV;       // 768
    constexpr int NW = JCHUNK / 32;          // 24 mask words per row-chunk
    __shared__ __align__(16) float2 lds_pq[JCHUNK];
    int b = blockIdx.x;
    int head = b & 7;
    int jc = (b >> 3) & (JCV - 1);
    int i0 = (b >> 3) / JCV * 64;
    int jbase = jc * JCHUNK;
    int tid = threadIdx.x;
    int wave = tid >> 6, lane = tid & 63;
    int fr = lane & 15, quad = lane >> 4;

    float Mg = dec_key(maxkey[head]);
    for (int j = tid; j < JCHUNK; j += 256) {
        float t = e_dst[(jbase + j) * NH + head] - Mg;   // <= 0
        lds_pq[j] = make_float2(__expf(t), __expf(0.2f * t));
    }
    __syncthreads();

    int irow = i0 + wave * 16 + fr;
    float u = e_src[irow * NH + head] + Mg;
    float A = (u > 0.f) ? 1.f : __expf(0.8f * u);
    float C = (u > 0.f) ? __expf(-0.8f * u) : 1.f;
    float T = __expf(-u);

    // mask bits for this row's j-chunk: 24 words, 6x uint4
    unsigned wb[NW];
    const uint4* bp = reinterpret_cast<const uint4*>(bits + irow * 96 + jc * NW);
#pragma unroll
    for (int o = 0; o < NW / 4; ++o) {
        uint4 v = bp[o];
        wb[4 * o] = v.x; wb[4 * o + 1] = v.y; wb[4 * o + 2] = v.z; wb[4 * o + 3] = v.w;
    }

    const __bf16* hTh = hT + (head * ND + fr) * NROW + jbase + quad * 8;

    f32x4 acc0 = {0,0,0,0}, acc1 = {0,0,0,0}, acc2 = {0,0,0,0}, acc3 = {0,0,0,0};
    float lsum = 0.f;

#pragma unroll
    for (int k = 0; k < NW; ++k) {
        int j0 = k * 32;
        unsigned w = wb[k] >> (quad * 8);
        bf16x8 v0 = *reinterpret_cast<const bf16x8*>(hTh + j0);
        bf16x8 v1 = *reinterpret_cast<const bf16x8*>(hTh + j0 + 16 * NROW);
        bf16x8 v2 = *reinterpret_cast<const bf16x8*>(hTh + j0 + 32 * NROW);
        bf16x8 v3 = *reinterpret_cast<const bf16x8*>(hTh + j0 + 48 * NROW);
        const float4* lp = reinterpret_cast<const float4*>(&lds_pq[j0 + quad * 8]);
        float4 q01 = lp[0], q23 = lp[1], q45 = lp[2], q67 = lp[3];
        float P[8] = {q01.x, q01.z, q23.x, q23.z, q45.x, q45.z, q67.x, q67.z};
        float Q[8] = {q01.y, q01.w, q23.y, q23.w, q45.y, q45.w, q67.y, q67.w};
        bf16x8 af;
#pragma unroll
        for (int t = 0; t < 8; ++t) {
            bool pos = P[t] > T;
            float p = (pos ? P[t] : Q[t]) * (pos ? A : C);
            p = ((w >> t) & 1u) ? p : 0.f;
            af[t] = (__bf16)p;
            lsum += p;
        }
        acc0 = __builtin_amdgcn_mfma_f32_16x16x32_bf16(af, v0, acc0, 0, 0, 0);
        acc1 = __builtin_amdgcn_mfma_f32_16x16x32_bf16(af, v1, acc1, 0, 0, 0);
        acc2 = __builtin_amdgcn_mfma_f32_16x16x32_bf16(af, v2, acc2, 0, 0, 0);
        acc3 = __builtin_amdgcn_mfma_f32_16x16x32_bf16(af, v3, acc3, 0, 0, 0);
    }

    lsum += __shfl_xor(lsum, 16, 64);
    lsum += __shfl_xor(lsum, 32, 64);    // lane L holds total for row (L&15)

    if (quad == 0)
        den[(jc * NROW + i0 + wave * 16 + fr) * NH + head] = lsum;

#pragma unroll
    for (int r = 0; r < 4; ++r) {
        int orow = quad * 4 + r;
        int ob = (jc * NROW + i0 + wave * 16 + orow) * NF + head * ND + fr;
        num[ob +  0] = acc0[r];
        num[ob + 16] = acc1[r];
        num[ob + 32] = acc2[r];
        num[ob + 48] = acc3[r];
    }
}

// ---------------------------------------------------------------------------
// Kernel 5: out[i,c] = sum_jc num[jc][i][c] / sum_jc den[jc][i][c>>6]
// ---------------------------------------------------------------------------
__global__ __launch_bounds__(256) void k_reduce(const float* __restrict__ num,
                                                const float* __restrict__ den,
                                                float* __restrict__ out, int jcv) {
    int idx = blockIdx.x * 256 + threadIdx.x;     // 0 .. NROW*NF
    int i = idx >> 9;
    int c = idx & 511;
    int head = c >> 6;
    float ns = 0.f, ds = 0.f;
    for (int k = 0; k < jcv; ++k) {
        ns += num[(k * NROW + i) * NF + c];
        ds += den[(k * NROW + i) * NH + head];
    }
    out[idx] = ns / fmaxf(ds, 1e-30f);
}

// ---------------------------------------------------------------------------
extern "C" void kernel_launch(void* const* d_in, const int* in_sizes, int n_in,
                              void* d_out, int out_size, void* d_ws, size_t ws_size,
                              hipStream_t stream) {
    const float* x_raw  = (const float*)d_in[0];
    const int*   adj    = (const int*)d_in[1];
    const float* W_raw  = (const float*)d_in[2];
    const float* as_raw = (const float*)d_in[3];
    const float* ad_raw = (const float*)d_in[4];
    float* out = (float*)d_out;

    char* ws = (char*)d_ws;
    __bf16*   h      = (__bf16*)(ws);                    // 3,145,728 B  (dead after k_edges)
    __bf16*   hT     = (__bf16*)(ws + 3145728);          // 3,145,728 B
    float*    e_src  = (float*)(ws + 6291456);           //    98,304 B
    float*    e_dst  = (float*)(ws + 6389760);           //    98,304 B
    unsigned* maxkey = (unsigned*)(ws + 6488064);        //        64 B
    unsigned* bits   = (unsigned*)(ws + 6488128);        // 1,179,648 B
    __bf16*   xb     = (__bf16*)(ws + 7667776);          // 3,145,728 B  (dead after gemm)
    __bf16*   Wb     = (__bf16*)(ws + 10813504);         //   524,288 B  (dead after gemm)
    // num/den OVERLAP xb/Wb (k_attn runs strictly after k_gemm_h).
    float*    num    = (float*)(ws + 7667776);           // JC*6,291,456 B

    // JC=4 peak: 7,667,776 + 4*6,291,456 + 4*98,304 = 33,226,816 B
    int jcv = (ws_size >= 33300000u) ? 4 : 1;
    float*    den    = (float*)(ws + 7667776 + (size_t)jcv * 6291456);

    k_convert<<<1024, 256, 0, stream>>>(x_raw, W_raw, xb, Wb, maxkey);
    k_bitpack<<<NROW, 256, 0, stream>>>(adj, (unsigned long long*)bits);
    k_gemm_h<<<1536, 256, 0, stream>>>(xb, Wb, h, hT);
    k_edges<<<NROW / 4, 256, 0, stream>>>(h, as_raw, ad_raw, e_src, e_dst, maxkey);
    if (jcv == 4)
        k_attn<4><<<48 * 4 * 8, 256, 0, stream>>>(bits, e_src, e_dst, maxkey, hT, num, den);
    else
        k_attn<1><<<48 * 1 * 8, 256, 0, stream>>>(bits, e_src, e_dst, maxkey, hT, num, den);
    k_reduce<<<NROW * NF / 256, 256, 0, stream>>>(num, den, out, jcv);
}

// Round 7
// 175.460 us; speedup vs baseline: 1.3367x; 1.2721x over previous
//
#include <hip/hip_runtime.h>
#include <hip/hip_bf16.h>

typedef __bf16 bf16x8 __attribute__((ext_vector_type(8)));
typedef float f32x4 __attribute__((ext_vector_type(4)));

#define NROW 3072
#define NF 512            // IN_F == H*D == 512
#define NH 8
#define ND 64

// Order-preserving float<->uint key for atomicMax over signed floats.
__device__ __forceinline__ unsigned enc_key(float f) {
    unsigned u = __float_as_uint(f);
    return (f < 0.f) ? ~u : (u | 0x80000000u);
}
__device__ __forceinline__ float dec_key(unsigned k) {
    unsigned u = (k & 0x80000000u) ? (k ^ 0x80000000u) : ~k;
    return __uint_as_float(u);
}

// ---------------------------------------------------------------------------
// Kernel 1: pack (adj>0 || j==i) into bitmask bits[3072][96] u32 (1.18 MB);
// also init maxkey (runs before k_fused in stream order).
// ---------------------------------------------------------------------------
__global__ __launch_bounds__(256) void k_bitpack(const int* __restrict__ adj,
                                                 unsigned long long* __restrict__ bits64,
                                                 unsigned* __restrict__ maxkey) {
    if (blockIdx.x == 0 && threadIdx.x < NH) maxkey[threadIdx.x] = 0u;
    int i = blockIdx.x;
    int wave = threadIdx.x >> 6, lane = threadIdx.x & 63;
    const int* row = adj + i * NROW;
#pragma unroll
    for (int it = 0; it < 12; ++it) {
        int base = wave * 768 + it * 64;
        int j = base + lane;
        bool pred = (row[j] > 0) || (j == i);
        unsigned long long bal = __ballot(pred);
        if (lane == 0) bits64[i * 48 + (base >> 6)] = bal;
    }
}

// ---------------------------------------------------------------------------
// Kernel 2 (fused front-end): per block = 16 i-rows x full 512 outputs.
// fp32->bf16 convert in-register, MFMA h, write hT (d-major), compute
// e_srcT/e_dstT [NH][NROW] + per-head global max.  Grid 192 x 512 threads.
// ---------------------------------------------------------------------------
__global__ __launch_bounds__(512) void k_fused(const float* __restrict__ x,
                                               const float* __restrict__ W,
                                               const float* __restrict__ a_src,
                                               const float* __restrict__ a_dst,
                                               __bf16* __restrict__ hT,
                                               float* __restrict__ e_srcT,
                                               float* __restrict__ e_dstT,
                                               unsigned* __restrict__ maxkey) {
    __shared__ __bf16 tile[16][NF + 8];          // 16x520x2B = 16,640 B
    __shared__ float a_s[NF], a_d[NF];           // 4 KB
    __shared__ unsigned skey[NH];
    int tid = threadIdx.x;
    int wave = tid >> 6, lane = tid & 63;
    int fr = lane & 15, quad = lane >> 4;
    int i0 = blockIdx.x * 16;
    int o0 = wave * 64;                          // each wave: 4 o-tiles of 16

    if (tid < NH) skey[tid] = 0u;
    a_s[tid] = a_src[tid];
    a_d[tid] = a_dst[tid];

    const float* xp = x + (i0 + fr) * NF + quad * 8;
    f32x4 acc[4] = {{0,0,0,0},{0,0,0,0},{0,0,0,0},{0,0,0,0}};
#pragma unroll
    for (int k = 0; k < 16; ++k) {
        float4 xa0 = *reinterpret_cast<const float4*>(xp + k * 32);
        float4 xa1 = *reinterpret_cast<const float4*>(xp + k * 32 + 4);
        bf16x8 af = { (__bf16)xa0.x, (__bf16)xa0.y, (__bf16)xa0.z, (__bf16)xa0.w,
                      (__bf16)xa1.x, (__bf16)xa1.y, (__bf16)xa1.z, (__bf16)xa1.w };
#pragma unroll
        for (int j = 0; j < 4; ++j) {
            const float* wp = W + (o0 + j * 16 + fr) * NF + k * 32 + quad * 8;
            float4 wb0 = *reinterpret_cast<const float4*>(wp);
            float4 wb1 = *reinterpret_cast<const float4*>(wp + 4);
            bf16x8 bf = { (__bf16)wb0.x, (__bf16)wb0.y, (__bf16)wb0.z, (__bf16)wb0.w,
                          (__bf16)wb1.x, (__bf16)wb1.y, (__bf16)wb1.z, (__bf16)wb1.w };
            acc[j] = __builtin_amdgcn_mfma_f32_16x16x32_bf16(af, bf, acc[j], 0, 0, 0);
        }
    }
    // D: row m = quad*4+r (i), col n = fr (o)
#pragma unroll
    for (int j = 0; j < 4; ++j)
#pragma unroll
        for (int r = 0; r < 4; ++r)
            tile[quad * 4 + r][o0 + j * 16 + fr] = (__bf16)acc[j][r];
    __syncthreads();

    // hT write: thread t owns output-channel o=t, writes 16 i's (32 B).
    {
        int o = tid;
        __bf16 col[16];
#pragma unroll
        for (int r = 0; r < 16; ++r) col[r] = tile[r][o];
        *reinterpret_cast<bf16x8*>(hT + o * NROW + i0)     = *reinterpret_cast<bf16x8*>(&col[0]);
        *reinterpret_cast<bf16x8*>(hT + o * NROW + i0 + 8) = *reinterpret_cast<bf16x8*>(&col[8]);
    }
    // edges: threads 0..127 -> (i, head)
    if (tid < 128) {
        int i = tid >> 3, hh = tid & 7;
        float ps = 0.f, pd = 0.f;
#pragma unroll
        for (int d = 0; d < ND; ++d) {
            float hv = (float)tile[i][hh * ND + d];
            ps += hv * a_s[hh * ND + d];
            pd += hv * a_d[hh * ND + d];
        }
        e_srcT[hh * NROW + i0 + i] = ps;
        e_dstT[hh * NROW + i0 + i] = pd;
        atomicMax(&skey[hh], enc_key(pd));
    }
    __syncthreads();
    if (tid < NH) atomicMax(&maxkey[tid], skey[tid]);
}

// ---------------------------------------------------------------------------
// Kernel 3: masked softmax-PV. hT chunks staged in LDS (double-buffered,
// frag-ordered: conflict-free ds_write/ds_read), shared by all 4 waves ->
// 4x cut in L2->VGPR streaming. Mask bits in registers. Factored exp.
// Grid: 48 i-blocks x JCV j-chunks x 8 heads; 4 waves; 16 rows/wave.
// ---------------------------------------------------------------------------
template <int JCV>
__global__ __launch_bounds__(256) void k_attn(const unsigned* __restrict__ bits,
                                              const float* __restrict__ e_srcT,
                                              const float* __restrict__ e_dstT,
                                              const unsigned* __restrict__ maxkey,
                                              const __bf16* __restrict__ hT,
                                              float* __restrict__ num,
                                              float* __restrict__ den) {
    constexpr int JCHUNK = NROW / JCV;       // 768
    constexpr int NW = JCHUNK / 32;          // 24 chunks of 32 j
    __shared__ __align__(16) float2 lds_pq[JCHUNK];      // 6144 B
    __shared__ __align__(16) __bf16 hbuf[2][2048];       // 2 x 4 KB
    int b = blockIdx.x;
    int head = b & 7;
    int jc = (b >> 3) & (JCV - 1);
    int i0 = (b >> 3) / JCV * 64;
    int jbase = jc * JCHUNK;
    int tid = threadIdx.x;
    int wave = tid >> 6, lane = tid & 63;
    int fr = lane & 15, quad = lane >> 4;

    float Mg = dec_key(maxkey[head]);
    for (int j = tid; j < JCHUNK; j += 256) {
        float t = e_dstT[head * NROW + jbase + j] - Mg;   // <= 0
        lds_pq[j] = make_float2(__expf(t), __expf(0.2f * t));
    }

    int irow = i0 + wave * 16 + fr;
    float u = e_srcT[head * NROW + irow] + Mg;
    float A = (u > 0.f) ? 1.f : __expf(0.8f * u);
    float C = (u > 0.f) ? __expf(-0.8f * u) : 1.f;
    float T = __expf(-u);

    // mask bits for this row's j-chunk: 24 words
    unsigned wb[NW];
    const uint4* bp = reinterpret_cast<const uint4*>(bits + irow * 96 + jc * NW);
#pragma unroll
    for (int o = 0; o < NW / 4; ++o) {
        uint4 v = bp[o];
        wb[4 * o] = v.x; wb[4 * o + 1] = v.y; wb[4 * o + 2] = v.z; wb[4 * o + 3] = v.w;
    }

    // staging: thread t=(wave,lane) fetches d = wave*16 + (lane&15),
    // j-sub = (lane>>4)*8, into hbuf at t*8 elems (16 B) -> frag order.
    const __bf16* gsrc = hT + (head * ND + wave * 16 + (lane & 15)) * NROW
                            + jbase + (lane >> 4) * 8;
    *reinterpret_cast<bf16x8*>(&hbuf[0][tid * 8]) = *reinterpret_cast<const bf16x8*>(gsrc);
    __syncthreads();

    f32x4 acc0 = {0,0,0,0}, acc1 = {0,0,0,0}, acc2 = {0,0,0,0}, acc3 = {0,0,0,0};
    float lsum = 0.f;

#pragma unroll 2
    for (int k = 0; k < NW; ++k) {
        if (k + 1 < NW)
            *reinterpret_cast<bf16x8*>(&hbuf[(k + 1) & 1][tid * 8]) =
                *reinterpret_cast<const bf16x8*>(gsrc + (k + 1) * 32);

        const __bf16* hb = &hbuf[k & 1][0];
        bf16x8 v0 = *reinterpret_cast<const bf16x8*>(hb + 0 * 512 + lane * 8);
        bf16x8 v1 = *reinterpret_cast<const bf16x8*>(hb + 1 * 512 + lane * 8);
        bf16x8 v2 = *reinterpret_cast<const bf16x8*>(hb + 2 * 512 + lane * 8);
        bf16x8 v3 = *reinterpret_cast<const bf16x8*>(hb + 3 * 512 + lane * 8);

        int j0 = k * 32;
        unsigned w = wb[k] >> (quad * 8);
        const float4* lp = reinterpret_cast<const float4*>(&lds_pq[j0 + quad * 8]);
        float4 q01 = lp[0], q23 = lp[1], q45 = lp[2], q67 = lp[3];
        float P[8] = {q01.x, q01.z, q23.x, q23.z, q45.x, q45.z, q67.x, q67.z};
        float Q[8] = {q01.y, q01.w, q23.y, q23.w, q45.y, q45.w, q67.y, q67.w};
        bf16x8 af;
#pragma unroll
        for (int t = 0; t < 8; ++t) {
            bool pos = P[t] > T;
            float p = (pos ? P[t] : Q[t]) * (pos ? A : C);
            p = ((w >> t) & 1u) ? p : 0.f;
            af[t] = (__bf16)p;
            lsum += p;
        }
        acc0 = __builtin_amdgcn_mfma_f32_16x16x32_bf16(af, v0, acc0, 0, 0, 0);
        acc1 = __builtin_amdgcn_mfma_f32_16x16x32_bf16(af, v1, acc1, 0, 0, 0);
        acc2 = __builtin_amdgcn_mfma_f32_16x16x32_bf16(af, v2, acc2, 0, 0, 0);
        acc3 = __builtin_amdgcn_mfma_f32_16x16x32_bf16(af, v3, acc3, 0, 0, 0);
        __syncthreads();
    }

    lsum += __shfl_xor(lsum, 16, 64);
    lsum += __shfl_xor(lsum, 32, 64);    // lane L holds total for row (L&15)

    if (quad == 0)
        den[(jc * NROW + i0 + wave * 16 + fr) * NH + head] = lsum;

#pragma unroll
    for (int r = 0; r < 4; ++r) {
        int orow = quad * 4 + r;
        int ob = (jc * NROW + i0 + wave * 16 + orow) * NF + head * ND + fr;
        num[ob +  0] = acc0[r];
        num[ob + 16] = acc1[r];
        num[ob + 32] = acc2[r];
        num[ob + 48] = acc3[r];
    }
}

// ---------------------------------------------------------------------------
// Kernel 4: out[i,c] = sum_jc num[jc][i][c] / sum_jc den[jc][i][c>>6]
// ---------------------------------------------------------------------------
__global__ __launch_bounds__(256) void k_reduce(const float* __restrict__ num,
                                                const float* __restrict__ den,
                                                float* __restrict__ out, int jcv) {
    int idx = blockIdx.x * 256 + threadIdx.x;     // 0 .. NROW*NF
    int i = idx >> 9;
    int c = idx & 511;
    int head = c >> 6;
    float ns = 0.f, ds = 0.f;
    for (int k = 0; k < jcv; ++k) {
        ns += num[(k * NROW + i) * NF + c];
        ds += den[(k * NROW + i) * NH + head];
    }
    out[idx] = ns / fmaxf(ds, 1e-30f);
}

// ---------------------------------------------------------------------------
extern "C" void kernel_launch(void* const* d_in, const int* in_sizes, int n_in,
                              void* d_out, int out_size, void* d_ws, size_t ws_size,
                              hipStream_t stream) {
    const float* x_raw  = (const float*)d_in[0];
    const int*   adj    = (const int*)d_in[1];
    const float* W_raw  = (const float*)d_in[2];
    const float* as_raw = (const float*)d_in[3];
    const float* ad_raw = (const float*)d_in[4];
    float* out = (float*)d_out;

    char* ws = (char*)d_ws;
    __bf16*   hT     = (__bf16*)(ws);                    // 3,145,728 B
    float*    e_srcT = (float*)(ws + 3145728);           //    98,304 B
    float*    e_dstT = (float*)(ws + 3244032);           //    98,304 B
    unsigned* maxkey = (unsigned*)(ws + 3342336);        //        64 B
    unsigned* bits   = (unsigned*)(ws + 3342400);        // 1,179,648 B
    float*    num    = (float*)(ws + 4522048);           // JC*6,291,456 B

    // JC=4 peak: 4,522,048 + 4*6,291,456 + 4*98,304 = 30,081,088 B
    int jcv = (ws_size >= 30200000u) ? 4 : 1;
    float*    den    = (float*)(ws + 4522048 + (size_t)jcv * 6291456);

    k_bitpack<<<NROW, 256, 0, stream>>>(adj, (unsigned long long*)bits, maxkey);
    k_fused<<<NROW / 16, 512, 0, stream>>>(x_raw, W_raw, as_raw, ad_raw,
                                           hT, e_srcT, e_dstT, maxkey);
    if (jcv == 4)
        k_attn<4><<<48 * 4 * 8, 256, 0, stream>>>(bits, e_srcT, e_dstT, maxkey, hT, num, den);
    else
        k_attn<1><<<48 * 1 * 8, 256, 0, stream>>>(bits, e_srcT, e_dstT, maxkey, hT, num, den);
    k_reduce<<<NROW * NF / 256, 256, 0, stream>>>(num, den, out, jcv);
}

// Round 8
// 171.484 us; speedup vs baseline: 1.3677x; 1.0232x over previous
//
#include <hip/hip_runtime.h>
#include <hip/hip_bf16.h>

typedef __bf16 bf16x8 __attribute__((ext_vector_type(8)));
typedef __bf16 bf16x4 __attribute__((ext_vector_type(4)));
typedef float f32x4 __attribute__((ext_vector_type(4)));

#define NROW 3072
#define NF 512            // IN_F == H*D == 512
#define NH 8
#define ND 64

// Order-preserving float<->uint key for atomicMax over signed floats.
__device__ __forceinline__ unsigned enc_key(float f) {
    unsigned u = __float_as_uint(f);
    return (f < 0.f) ? ~u : (u | 0x80000000u);
}
__device__ __forceinline__ float dec_key(unsigned k) {
    unsigned u = (k & 0x80000000u) ? (k ^ 0x80000000u) : ~k;
    return __uint_as_float(u);
}

// ---------------------------------------------------------------------------
// Kernel 0: W fp32 -> bf16 (once); init maxkey.
// ---------------------------------------------------------------------------
__global__ __launch_bounds__(256) void k_convW(const float* __restrict__ W,
                                               __bf16* __restrict__ Wb,
                                               unsigned* __restrict__ maxkey) {
    if (blockIdx.x == 0 && threadIdx.x < NH) maxkey[threadIdx.x] = 0u;
    int k = blockIdx.x * 256 + threadIdx.x;          // 65536 float4s
    float4 v = reinterpret_cast<const float4*>(W)[k];
    bf16x4 o = { (__bf16)v.x, (__bf16)v.y, (__bf16)v.z, (__bf16)v.w };
    *reinterpret_cast<bf16x4*>(Wb + k * 4) = o;
}

// ---------------------------------------------------------------------------
// Kernel 1: pack (adj>0 || j==i) into bitmask bits[3072][96] u32 (1.18 MB).
// ---------------------------------------------------------------------------
__global__ __launch_bounds__(256) void k_bitpack(const int* __restrict__ adj,
                                                 unsigned long long* __restrict__ bits64) {
    int i = blockIdx.x;
    int wave = threadIdx.x >> 6, lane = threadIdx.x & 63;
    const int* row = adj + i * NROW;
#pragma unroll
    for (int it = 0; it < 12; ++it) {
        int base = wave * 768 + it * 64;
        int j = base + lane;
        bool pred = (row[j] > 0) || (j == i);
        unsigned long long bal = __ballot(pred);
        if (lane == 0) bits64[i * 48 + (base >> 6)] = bal;
    }
}

// ---------------------------------------------------------------------------
// Kernel 2: h = x @ W^T; x converted fp32->bf16 in-register; write hT only
// (per-head d-major) via LDS transpose. 1536 blocks x 4 wave-tiles (16x16).
// ---------------------------------------------------------------------------
__global__ __launch_bounds__(256) void k_gemm(const float* __restrict__ x,
                                              const __bf16* __restrict__ Wb,
                                              __bf16* __restrict__ hT) {
    __shared__ __bf16 tile[4][16][17];
    int wave = threadIdx.x >> 6;
    int lane = threadIdx.x & 63;
    int t = blockIdx.x * 4 + wave;          // 6144 tiles: 192 i-tiles x 32 o-tiles
    int i0 = (t >> 5) << 4;
    int o0 = (t & 31) << 4;
    int fr = lane & 15;
    int quad = lane >> 4;

    const float* xp = x + (i0 + fr) * NF + quad * 8;
    const bf16x8* wp = reinterpret_cast<const bf16x8*>(Wb + (o0 + fr) * NF + quad * 8);

    f32x4 acc = {0.f, 0.f, 0.f, 0.f};
#pragma unroll
    for (int k = 0; k < 16; ++k) {
        float4 x0 = *reinterpret_cast<const float4*>(xp + k * 32);
        float4 x1 = *reinterpret_cast<const float4*>(xp + k * 32 + 4);
        bf16x8 a = { (__bf16)x0.x, (__bf16)x0.y, (__bf16)x0.z, (__bf16)x0.w,
                     (__bf16)x1.x, (__bf16)x1.y, (__bf16)x1.z, (__bf16)x1.w };
        bf16x8 b = wp[k * 4];
        acc = __builtin_amdgcn_mfma_f32_16x16x32_bf16(a, b, acc, 0, 0, 0);
    }
#pragma unroll
    for (int r = 0; r < 4; ++r)
        tile[wave][quad * 4 + r][fr] = (__bf16)acc[r];
    __syncthreads();
    int orow = lane >> 2;
    int li = (lane & 3) * 4;
    bf16x4 o4 = { tile[wave][li][orow], tile[wave][li + 1][orow],
                  tile[wave][li + 2][orow], tile[wave][li + 3][orow] };
    *reinterpret_cast<bf16x4*>(hT + (o0 + orow) * NROW + i0 + li) = o4;
}

// ---------------------------------------------------------------------------
// Kernel 3: e_srcT[h][i], e_dstT[h][i] from hT (coalesced row reads) + fused
// per-head global max. Grid dim3(12, 8): blockIdx.x = i-chunk, .y = head.
// ---------------------------------------------------------------------------
__global__ __launch_bounds__(256) void k_edgesT(const __bf16* __restrict__ hT,
                                                const float* __restrict__ a_src,
                                                const float* __restrict__ a_dst,
                                                float* __restrict__ e_srcT,
                                                float* __restrict__ e_dstT,
                                                unsigned* __restrict__ maxkey) {
    int hh = blockIdx.y;
    int i = blockIdx.x * 256 + threadIdx.x;
    float ps = 0.f, pd = 0.f;
#pragma unroll
    for (int d = 0; d < ND; ++d) {
        float hv = (float)hT[(hh * ND + d) * NROW + i];
        ps += hv * a_src[hh * ND + d];
        pd += hv * a_dst[hh * ND + d];
    }
    e_srcT[hh * NROW + i] = ps;
    e_dstT[hh * NROW + i] = pd;
    float mx = pd;
#pragma unroll
    for (int off = 1; off < 64; off <<= 1) mx = fmaxf(mx, __shfl_xor(mx, off, 64));
    if ((threadIdx.x & 63) == 0) atomicMax(&maxkey[hh], enc_key(mx));
}

// ---------------------------------------------------------------------------
// Kernel 4: masked softmax-PV. 128 i-rows per block (8 waves) share each
// LDS-staged 64-j hT chunk (double-buffered, frag-ordered, conflict-free).
// den computed by MFMA against a ones-vector (acc4) -> no per-p sum VALU.
// Factored exp: p = mask * (P_j>T_i ? A_i*P_j : C_i*Q_j).
// Grid: 24 i-blocks x JCV j-chunks x 8 heads.
// ---------------------------------------------------------------------------
template <int JCV>
__global__ __launch_bounds__(512) void k_attn(const unsigned* __restrict__ bits,
                                              const float* __restrict__ e_srcT,
                                              const float* __restrict__ e_dstT,
                                              const unsigned* __restrict__ maxkey,
                                              const __bf16* __restrict__ hT,
                                              float* __restrict__ num,
                                              float* __restrict__ den) {
    constexpr int JCHUNK = NROW / JCV;       // 768 (JCV=4)
    constexpr int NC = JCHUNK / 64;          // 12 chunks of 64 j
    __shared__ __align__(16) float2 lds_pq[JCHUNK];      // 6 KB (JCV=4)
    __shared__ __align__(16) __bf16 hbuf[2][4096];       // 2 x 8 KB
    int b = blockIdx.x;
    int head = b & 7;
    int jc = (b >> 3) & (JCV - 1);
    int i0 = ((b >> 3) / JCV) * 128;
    int jbase = jc * JCHUNK;
    int tid = threadIdx.x;
    int wave = tid >> 6, lane = tid & 63;
    int fr = lane & 15, quad = lane >> 4;

    float Mg = dec_key(maxkey[head]);
    for (int j = tid; j < JCHUNK; j += 512) {
        float t = e_dstT[head * NROW + jbase + j] - Mg;   // <= 0
        lds_pq[j] = make_float2(__expf(t), __expf(0.2f * t));
    }

    int irow = i0 + wave * 16 + fr;
    float u = e_srcT[head * NROW + irow] + Mg;
    float A = (u > 0.f) ? 1.f : __expf(0.8f * u);
    float C = (u > 0.f) ? __expf(-0.8f * u) : 1.f;
    float T = __expf(-u);

    const unsigned* brow = bits + irow * 96 + jc * (JCHUNK / 32);

    // staging map: thread t -> d = ((t>>6)&3)*16 + (t&15), j-off = ((t>>8)&1)*32
    // + ((t>>4)&3)*8; LDS dest = hbuf[buf][t*8]  (frag order, lane*16B).
    const __bf16* gsrc = hT + (head * ND + ((tid >> 6) & 3) * 16 + (tid & 15)) * NROW
                            + jbase + ((tid >> 8) & 1) * 32 + ((tid >> 4) & 3) * 8;
    *reinterpret_cast<bf16x8*>(&hbuf[0][tid * 8]) = *reinterpret_cast<const bf16x8*>(gsrc);
    __syncthreads();

    const bf16x8 ones = { (__bf16)1.f, (__bf16)1.f, (__bf16)1.f, (__bf16)1.f,
                          (__bf16)1.f, (__bf16)1.f, (__bf16)1.f, (__bf16)1.f };
    f32x4 acc0 = {0,0,0,0}, acc1 = {0,0,0,0}, acc2 = {0,0,0,0}, acc3 = {0,0,0,0};
    f32x4 acc4 = {0,0,0,0};
    uint2 wm = *reinterpret_cast<const uint2*>(brow);

    for (int k = 0; k < NC; ++k) {
        uint2 wmn;
        if (k + 1 < NC) {
            *reinterpret_cast<bf16x8*>(&hbuf[(k + 1) & 1][tid * 8]) =
                *reinterpret_cast<const bf16x8*>(gsrc + (k + 1) * 64);
            wmn = *reinterpret_cast<const uint2*>(brow + (k + 1) * 2);
        }
        const __bf16* hb = &hbuf[k & 1][0];
#pragma unroll
        for (int jh = 0; jh < 2; ++jh) {
            int j0 = k * 64 + jh * 32;
            unsigned w = (jh ? wm.y : wm.x) >> (quad * 8);
            bf16x8 v0 = *reinterpret_cast<const bf16x8*>(hb + jh * 2048 + 0 * 512 + lane * 8);
            bf16x8 v1 = *reinterpret_cast<const bf16x8*>(hb + jh * 2048 + 1 * 512 + lane * 8);
            bf16x8 v2 = *reinterpret_cast<const bf16x8*>(hb + jh * 2048 + 2 * 512 + lane * 8);
            bf16x8 v3 = *reinterpret_cast<const bf16x8*>(hb + jh * 2048 + 3 * 512 + lane * 8);
            const float4* lp = reinterpret_cast<const float4*>(&lds_pq[j0 + quad * 8]);
            float4 q01 = lp[0], q23 = lp[1], q45 = lp[2], q67 = lp[3];
            float P[8] = {q01.x, q01.z, q23.x, q23.z, q45.x, q45.z, q67.x, q67.z};
            float Q[8] = {q01.y, q01.w, q23.y, q23.w, q45.y, q45.w, q67.y, q67.w};
            bf16x8 af;
#pragma unroll
            for (int t = 0; t < 8; ++t) {
                bool pos = P[t] > T;
                float p = (pos ? P[t] : Q[t]) * (pos ? A : C);
                af[t] = ((w >> t) & 1u) ? (__bf16)p : (__bf16)0.f;
            }
            acc0 = __builtin_amdgcn_mfma_f32_16x16x32_bf16(af, v0, acc0, 0, 0, 0);
            acc1 = __builtin_amdgcn_mfma_f32_16x16x32_bf16(af, v1, acc1, 0, 0, 0);
            acc2 = __builtin_amdgcn_mfma_f32_16x16x32_bf16(af, v2, acc2, 0, 0, 0);
            acc3 = __builtin_amdgcn_mfma_f32_16x16x32_bf16(af, v3, acc3, 0, 0, 0);
            acc4 = __builtin_amdgcn_mfma_f32_16x16x32_bf16(af, ones, acc4, 0, 0, 0);
        }
        wm = wmn;
        __syncthreads();
    }

    // den: acc4 rows hold sum_j p (replicated across cols); rows m=quad*4+r
    if (fr == 0) {
#pragma unroll
        for (int r = 0; r < 4; ++r)
            den[(jc * NROW + i0 + wave * 16 + quad * 4 + r) * NH + head] = acc4[r];
    }
#pragma unroll
    for (int r = 0; r < 4; ++r) {
        int orow = quad * 4 + r;
        int ob = (jc * NROW + i0 + wave * 16 + orow) * NF + head * ND + fr;
        num[ob +  0] = acc0[r];
        num[ob + 16] = acc1[r];
        num[ob + 32] = acc2[r];
        num[ob + 48] = acc3[r];
    }
}

// ---------------------------------------------------------------------------
// Kernel 5: out[i,c] = sum_jc num[jc][i][c] / sum_jc den[jc][i][c>>6]
// ---------------------------------------------------------------------------
__global__ __launch_bounds__(256) void k_reduce(const float* __restrict__ num,
                                                const float* __restrict__ den,
                                                float* __restrict__ out, int jcv) {
    int idx = blockIdx.x * 256 + threadIdx.x;     // 0 .. NROW*NF
    int i = idx >> 9;
    int c = idx & 511;
    int head = c >> 6;
    float ns = 0.f, ds = 0.f;
    for (int k = 0; k < jcv; ++k) {
        ns += num[(k * NROW + i) * NF + c];
        ds += den[(k * NROW + i) * NH + head];
    }
    out[idx] = ns / fmaxf(ds, 1e-30f);
}

// ---------------------------------------------------------------------------
extern "C" void kernel_launch(void* const* d_in, const int* in_sizes, int n_in,
                              void* d_out, int out_size, void* d_ws, size_t ws_size,
                              hipStream_t stream) {
    const float* x_raw  = (const float*)d_in[0];
    const int*   adj    = (const int*)d_in[1];
    const float* W_raw  = (const float*)d_in[2];
    const float* as_raw = (const float*)d_in[3];
    const float* ad_raw = (const float*)d_in[4];
    float* out = (float*)d_out;

    char* ws = (char*)d_ws;
    __bf16*   hT     = (__bf16*)(ws);                    // 3,145,728 B
    float*    e_srcT = (float*)(ws + 3145728);           //    98,304 B
    float*    e_dstT = (float*)(ws + 3244032);           //    98,304 B
    unsigned* maxkey = (unsigned*)(ws + 3342336);        //        64 B
    unsigned* bits   = (unsigned*)(ws + 3342400);        // 1,179,648 B
    __bf16*   Wb     = (__bf16*)(ws + 4522048);          //   524,288 B
    float*    num    = (float*)(ws + 5046336);           // JC*6,291,456 B

    // JC=4 peak: 5,046,336 + 4*6,291,456 + 4*98,304 = 30,605,376 B
    int jcv = (ws_size >= 30700000u) ? 4 : 1;
    float*    den    = (float*)(ws + 5046336 + (size_t)jcv * 6291456);

    k_convW<<<256, 256, 0, stream>>>(W_raw, Wb, maxkey);
    k_bitpack<<<NROW, 256, 0, stream>>>(adj, (unsigned long long*)bits);
    k_gemm<<<1536, 256, 0, stream>>>(x_raw, Wb, hT);
    k_edgesT<<<dim3(12, 8), 256, 0, stream>>>(hT, as_raw, ad_raw, e_srcT, e_dstT, maxkey);
    if (jcv == 4)
        k_attn<4><<<24 * 4 * 8, 512, 0, stream>>>(bits, e_srcT, e_dstT, maxkey, hT, num, den);
    else
        k_attn<1><<<24 * 1 * 8, 512, 0, stream>>>(bits, e_srcT, e_dstT, maxkey, hT, num, den);
    k_reduce<<<NROW * NF / 256, 256, 0, stream>>>(num, den, out, jcv);
}